// Round 3
// baseline (663.738 us; speedup 1.0000x reference)
//
#include <hip/hip_runtime.h>
#include <cstddef>

#define B_ 16
#define T_ 64
#define N_ 1024
#define D_ 32
#define H_ 64
#define C_ 32
#define O_ 12

__device__ __forceinline__ float d_tanhf(float v){ float e = __expf(2.f*v); return 1.f - 2.f/(e + 1.f); }
__device__ __forceinline__ float d_sigmf(float v){ return 1.f/(1.f + __expf(-v)); }

// ---------------- K1: U[b,n,0:64]=m1, U[b,n,64:128]=m2 ----------------
__global__ __launch_bounds__(128) void k_u(const float* __restrict__ x,
    const float* __restrict__ w1, const float* __restrict__ b1,
    const float* __restrict__ w2, const float* __restrict__ b2,
    float* __restrict__ U)
{
  int row = blockIdx.x;               // b*N + n
  int b = row >> 10, n = row & (N_-1);
  int t = threadIdx.x;
  int hh = t & (H_-1), which = t >> 6;
  __shared__ float xl[D_];
  if (t < D_) xl[t] = x[(((size_t)b*T_ + (T_-1))*N_ + n)*D_ + t];
  __syncthreads();
  const float* w  = which ? w2 : w1;
  const float* bi = which ? b2 : b1;
  float acc = bi[hh];
  #pragma unroll
  for (int d = 0; d < D_; ++d) acc += xl[d] * w[d*H_ + hh];
  U[(size_t)row*128 + which*H_ + hh] = acc;
}

// ---------------- K2: adj = softmax(tanh(S)), single-pass, exp in registers ----------------
// S[n,m] = sum_k U[n,k] * U[m,(k+64)&127]. Block: 64 n-rows x full m. 512 thr.
#define ADJ_S4 33   // float4 row stride (132 words => 4*row mod 32 bank spread)
__global__ __launch_bounds__(512, 1) void k_adj(const float* __restrict__ U, float* __restrict__ adj)
{
  __shared__ float4 Un4[64*ADJ_S4];    // 33.8 KB
  __shared__ float4 Um4[128*ADJ_S4];   // 67.6 KB
  int b  = blockIdx.x >> 4;
  int n0 = (blockIdx.x & 15) * 64;
  int tid = threadIdx.x;
  int tx = tid & 31, ty = tid >> 5;    // ty 0..15
  const float4* Ub4 = reinterpret_cast<const float4*>(U + (size_t)b*N_*128);
  float* aout = adj + (size_t)b*N_*N_ + (size_t)n0*N_;

  for (int l = tid; l < 64*32; l += 512) {
    int r = l >> 5, k4 = l & 31;
    Un4[r*ADJ_S4 + k4] = Ub4[(size_t)(n0 + r)*32 + k4];
  }

  float eAll[8][4][4];
  float rs[4] = {0.f,0.f,0.f,0.f};

  #pragma unroll
  for (int mc = 0; mc < 8; ++mc) {
    int m0 = mc * 128;
    __syncthreads();
    for (int l = tid; l < 128*32; l += 512) {
      int r = l >> 5, k4 = l & 31;
      Um4[r*ADJ_S4 + ((k4 + 16) & 31)] = Ub4[(size_t)(m0 + r)*32 + k4];  // swap 64-float halves
    }
    __syncthreads();

    float acc[4][4];
    #pragma unroll
    for (int j=0;j<4;++j)
      #pragma unroll
      for (int i=0;i<4;++i) acc[j][i]=0.f;

    #pragma unroll 8
    for (int k4 = 0; k4 < 32; ++k4) {
      float4 un[4], um[4];
      #pragma unroll
      for (int j=0;j<4;++j) un[j] = Un4[(ty + 16*j)*ADJ_S4 + k4];
      #pragma unroll
      for (int i=0;i<4;++i) um[i] = Um4[(tx + 32*i)*ADJ_S4 + k4];
      #pragma unroll
      for (int j=0;j<4;++j)
        #pragma unroll
        for (int i=0;i<4;++i)
          acc[j][i] += un[j].x*um[i].x + un[j].y*um[i].y + un[j].z*um[i].z + un[j].w*um[i].w;
    }
    #pragma unroll
    for (int j=0;j<4;++j)
      #pragma unroll
      for (int i=0;i<4;++i) {
        float E = __expf(d_tanhf(acc[j][i]));
        eAll[mc][j][i] = E;
        rs[j] += E;
      }
  }

  // full row sum: reduce over the 32 tx lanes (stay within wave half)
  float inv[4];
  #pragma unroll
  for (int j=0;j<4;++j) {
    float s = rs[j];
    s += __shfl_xor(s, 1);
    s += __shfl_xor(s, 2);
    s += __shfl_xor(s, 4);
    s += __shfl_xor(s, 8);
    s += __shfl_xor(s, 16);
    inv[j] = 1.0f / s;
  }

  #pragma unroll
  for (int mc = 0; mc < 8; ++mc) {
    #pragma unroll
    for (int j=0;j<4;++j) {
      float* rowp = aout + (size_t)(ty + 16*j)*N_ + mc*128 + tx;
      #pragma unroll
      for (int i=0;i<4;++i)
        rowp[32*i] = eAll[mc][j][i] * inv[j];
    }
  }
}

// ---------------- K3: gated dilated convs, last-position only -> h ----------------
__global__ __launch_bounds__(256) void k_conv(const float* __restrict__ x,
    const float* __restrict__ fw1,const float* __restrict__ fb1,const float* __restrict__ gw1,const float* __restrict__ gb1,
    const float* __restrict__ fw2,const float* __restrict__ fb2,const float* __restrict__ gw2,const float* __restrict__ gb2,
    const float* __restrict__ fw3,const float* __restrict__ fb3,const float* __restrict__ gw3,const float* __restrict__ gb3,
    float* __restrict__ h)
{
  __shared__ float xs[16][15][32];
  __shared__ float y1[16][7][32];
  __shared__ float y2[16][3][32];
  int tid = threadIdx.x;
  int b  = blockIdx.x >> 6;
  int n0 = (blockIdx.x & 63) * 16;

  for (int l = tid; l < 1920; l += 256) {
    int t = l >> 7, r = l & 127;
    int nl = r >> 3, d4 = r & 7;
    float4 v = reinterpret_cast<const float4*>(x)[(((size_t)b*T_ + 49 + t)*N_ + n0 + nl)*8 + d4];
    *reinterpret_cast<float4*>(&xs[nl][t][d4*4]) = v;
  }
  __syncthreads();

  int sg = tid >> 5, c = tid & 31;

  float af[2][7], ag[2][7];
  {
    float bf = fb1[c], bg = gb1[c];
    #pragma unroll
    for (int ss=0; ss<2; ++ss)
      #pragma unroll
      for (int p=0;p<7;++p){ af[ss][p]=bf; ag[ss][p]=bg; }
  }
  for (int icb = 0; icb < 4; ++icb) {
    float wfl[24], wgl[24];
    #pragma unroll
    for (int q = 0; q < 6; ++q) {
      float4 a = reinterpret_cast<const float4*>(fw1)[c*24 + icb*6 + q];
      float4 g = reinterpret_cast<const float4*>(gw1)[c*24 + icb*6 + q];
      wfl[q*4+0]=a.x; wfl[q*4+1]=a.y; wfl[q*4+2]=a.z; wfl[q*4+3]=a.w;
      wgl[q*4+0]=g.x; wgl[q*4+1]=g.y; wgl[q*4+2]=g.z; wgl[q*4+3]=g.w;
    }
    #pragma unroll
    for (int ic8 = 0; ic8 < 8; ++ic8) {
      int ic = icb*8 + ic8;
      #pragma unroll
      for (int ss=0; ss<2; ++ss) {
        int s = sg*2 + ss;
        float xv[15];
        #pragma unroll
        for (int t=0;t<15;++t) xv[t] = xs[s][t][ic];
        #pragma unroll
        for (int p=0;p<7;++p){
          #pragma unroll
          for (int k=0;k<3;++k){
            af[ss][p] += xv[2*p+k]*wfl[ic8*3+k];
            ag[ss][p] += xv[2*p+k]*wgl[ic8*3+k];
          }
        }
      }
    }
  }
  #pragma unroll
  for (int ss=0; ss<2; ++ss)
    #pragma unroll
    for (int p=0;p<7;++p) y1[sg*2+ss][p][c] = d_tanhf(af[ss][p]) * d_sigmf(ag[ss][p]);
  __syncthreads();

  float af2[2][3], ag2[2][3];
  {
    float bf = fb2[c], bg = gb2[c];
    #pragma unroll
    for (int ss=0; ss<2; ++ss)
      #pragma unroll
      for (int r=0;r<3;++r){ af2[ss][r]=bf; ag2[ss][r]=bg; }
  }
  for (int icb = 0; icb < 4; ++icb) {
    float wfl[24], wgl[24];
    #pragma unroll
    for (int q = 0; q < 6; ++q) {
      float4 a = reinterpret_cast<const float4*>(fw2)[c*24 + icb*6 + q];
      float4 g = reinterpret_cast<const float4*>(gw2)[c*24 + icb*6 + q];
      wfl[q*4+0]=a.x; wfl[q*4+1]=a.y; wfl[q*4+2]=a.z; wfl[q*4+3]=a.w;
      wgl[q*4+0]=g.x; wgl[q*4+1]=g.y; wgl[q*4+2]=g.z; wgl[q*4+3]=g.w;
    }
    #pragma unroll
    for (int ic8 = 0; ic8 < 8; ++ic8) {
      int ic = icb*8 + ic8;
      #pragma unroll
      for (int ss=0; ss<2; ++ss) {
        int s = sg*2 + ss;
        float yv[7];
        #pragma unroll
        for (int j=0;j<7;++j) yv[j] = y1[s][j][ic];
        #pragma unroll
        for (int r=0;r<3;++r){
          #pragma unroll
          for (int k=0;k<3;++k){
            af2[ss][r] += yv[2*r+k]*wfl[ic8*3+k];
            ag2[ss][r] += yv[2*r+k]*wgl[ic8*3+k];
          }
        }
      }
    }
  }
  #pragma unroll
  for (int ss=0; ss<2; ++ss)
    #pragma unroll
    for (int r=0;r<3;++r) y2[sg*2+ss][r][c] = d_tanhf(af2[ss][r]) * d_sigmf(ag2[ss][r]);
  __syncthreads();

  float af3[2], ag3[2];
  {
    float bf = fb3[c], bg = gb3[c];
    af3[0]=bf; af3[1]=bf; ag3[0]=bg; ag3[1]=bg;
  }
  for (int icb = 0; icb < 4; ++icb) {
    float wfl[24], wgl[24];
    #pragma unroll
    for (int q = 0; q < 6; ++q) {
      float4 a = reinterpret_cast<const float4*>(fw3)[c*24 + icb*6 + q];
      float4 g = reinterpret_cast<const float4*>(gw3)[c*24 + icb*6 + q];
      wfl[q*4+0]=a.x; wfl[q*4+1]=a.y; wfl[q*4+2]=a.z; wfl[q*4+3]=a.w;
      wgl[q*4+0]=g.x; wgl[q*4+1]=g.y; wgl[q*4+2]=g.z; wgl[q*4+3]=g.w;
    }
    #pragma unroll
    for (int ic8 = 0; ic8 < 8; ++ic8) {
      int ic = icb*8 + ic8;
      #pragma unroll
      for (int ss=0; ss<2; ++ss) {
        int s = sg*2 + ss;
        float yv[3];
        #pragma unroll
        for (int r=0;r<3;++r) yv[r] = y2[s][r][ic];
        #pragma unroll
        for (int k=0;k<3;++k){
          af3[ss] += yv[k]*wfl[ic8*3+k];
          ag3[ss] += yv[k]*wgl[ic8*3+k];
        }
      }
    }
  }
  #pragma unroll
  for (int ss=0; ss<2; ++ss)
    h[((size_t)b*N_ + n0 + sg*2 + ss)*C_ + c] = d_tanhf(af3[ss]) * d_sigmf(ag3[ss]);
}

// ---------------- K4: z_out = 0.1 h + 0.45 z + 0.45 adj@z ----------------
// Block 256 thr: 64 rows x 32 ch; thread: 2 rows (rq, rq+32) x 4 ch (c4).
#define PROP_S4 33
__global__ __launch_bounds__(256) void k_prop(const float* __restrict__ adj, const float* __restrict__ h,
                                              const float* __restrict__ zin, float* __restrict__ zout)
{
  __shared__ float4 at4[64*PROP_S4];  // 33.8 KB
  __shared__ float4 zt4[1024];        // 16 KB
  int b  = blockIdx.x >> 4;
  int n0 = (blockIdx.x & 15) * 64;
  int tid = threadIdx.x;
  int c4 = tid & 7, rq = tid >> 3;    // rq 0..31

  const float4* adj4 = reinterpret_cast<const float4*>(adj);
  const float4* zin4 = reinterpret_cast<const float4*>(zin);
  const float4* h4   = reinterpret_cast<const float4*>(h);

  float4 acc0 = {0.f,0.f,0.f,0.f}, acc1 = {0.f,0.f,0.f,0.f};

  for (int mc = 0; mc < 8; ++mc) {
    int m0 = mc * 128;
    __syncthreads();
    for (int l = tid; l < 64*32; l += 256) {
      int rr = l >> 5, cc = l & 31;
      at4[rr*PROP_S4 + cc] = adj4[(size_t)(b*N_ + n0 + rr)*256 + mc*32 + cc];
    }
    for (int l = tid; l < 1024; l += 256)
      zt4[l] = zin4[(size_t)(b*N_ + m0)*8 + l];
    __syncthreads();

    #pragma unroll 8
    for (int mm4 = 0; mm4 < 32; ++mm4) {
      float4 a0 = at4[rq*PROP_S4 + mm4];
      float4 a1 = at4[(rq+32)*PROP_S4 + mm4];
      float4 z0 = zt4[(mm4*4+0)*8 + c4];
      float4 z1 = zt4[(mm4*4+1)*8 + c4];
      float4 z2 = zt4[(mm4*4+2)*8 + c4];
      float4 z3 = zt4[(mm4*4+3)*8 + c4];
      acc0.x += a0.x*z0.x + a0.y*z1.x + a0.z*z2.x + a0.w*z3.x;
      acc0.y += a0.x*z0.y + a0.y*z1.y + a0.z*z2.y + a0.w*z3.y;
      acc0.z += a0.x*z0.z + a0.y*z1.z + a0.z*z2.z + a0.w*z3.z;
      acc0.w += a0.x*z0.w + a0.y*z1.w + a0.z*z2.w + a0.w*z3.w;
      acc1.x += a1.x*z0.x + a1.y*z1.x + a1.z*z2.x + a1.w*z3.x;
      acc1.y += a1.x*z0.y + a1.y*z1.y + a1.z*z2.y + a1.w*z3.y;
      acc1.z += a1.x*z0.z + a1.y*z1.z + a1.z*z2.z + a1.w*z3.z;
      acc1.w += a1.x*z0.w + a1.y*z1.w + a1.z*z2.w + a1.w*z3.w;
    }
  }

  #pragma unroll
  for (int q = 0; q < 2; ++q) {
    float4 acc = q ? acc1 : acc0;
    size_t o = (size_t)(b*N_ + n0 + rq + 32*q)*8 + c4;
    float4 hv = h4[o], zv = zin4[o], res;
    res.x = 0.1f*hv.x + 0.45f*zv.x + 0.45f*acc.x;
    res.y = 0.1f*hv.y + 0.45f*zv.y + 0.45f*acc.y;
    res.z = 0.1f*hv.z + 0.45f*zv.z + 0.45f*acc.z;
    res.w = 0.1f*hv.w + 0.45f*zv.w + 0.45f*acc.w;
    reinterpret_cast<float4*>(zout)[o] = res;
  }
}

// ---------------- K5: out = relu(z) @ wo + bo ----------------
__global__ __launch_bounds__(256) void k_out(const float* __restrict__ z, const float* __restrict__ wo,
                                             const float* __restrict__ bo, float* __restrict__ out)
{
  int gid = blockIdx.x*256 + threadIdx.x;
  if (gid >= B_*N_*O_) return;
  int o = gid % O_; int row = gid / O_;
  const float* zr = z + (size_t)row*C_;
  float acc = bo[o];
  #pragma unroll
  for (int cc = 0; cc < C_; ++cc) acc += fmaxf(zr[cc], 0.f) * wo[cc*O_ + o];
  out[gid] = acc;
}

extern "C" void kernel_launch(void* const* d_in, const int* in_sizes, int n_in,
                              void* d_out, int out_size, void* d_ws, size_t ws_size,
                              hipStream_t stream)
{
  const float* x   = (const float*)d_in[0];
  const float* w1  = (const float*)d_in[1];
  const float* b1  = (const float*)d_in[2];
  const float* w2  = (const float*)d_in[3];
  const float* b2  = (const float*)d_in[4];
  const float* fw1 = (const float*)d_in[5];  const float* fb1 = (const float*)d_in[6];
  const float* gw1 = (const float*)d_in[7];  const float* gb1 = (const float*)d_in[8];
  const float* fw2 = (const float*)d_in[9];  const float* fb2 = (const float*)d_in[10];
  const float* gw2 = (const float*)d_in[11]; const float* gb2 = (const float*)d_in[12];
  const float* fw3 = (const float*)d_in[13]; const float* fb3 = (const float*)d_in[14];
  const float* gw3 = (const float*)d_in[15]; const float* gb3 = (const float*)d_in[16];
  const float* wo  = (const float*)d_in[17]; const float* bo  = (const float*)d_in[18];

  float* out = (float*)d_out;
  float* adj = out + (size_t)B_*N_*O_;

  float* U  = (float*)d_ws;                     // [B][N][128]
  float* h  = U  + (size_t)B_*N_*128;           // [B][N][32]
  float* z0 = h  + (size_t)B_*N_*32;
  float* z1 = z0 + (size_t)B_*N_*32;

  k_u<<<B_*N_, 128, 0, stream>>>(x, w1, b1, w2, b2, U);
  k_adj<<<B_*16, 512, 0, stream>>>(U, adj);
  k_conv<<<B_*N_/16, 256, 0, stream>>>(x, fw1,fb1,gw1,gb1, fw2,fb2,gw2,gb2, fw3,fb3,gw3,gb3, h);

  const float* zi = h;
  float* zbuf[2] = {z0, z1};
  for (int it = 0; it < 10; ++it) {
    float* zo = zbuf[it & 1];
    k_prop<<<B_*16, 256, 0, stream>>>(adj, h, zi, zo);
    zi = zo;
  }
  k_out<<<(B_*N_*O_ + 255)/256, 256, 0, stream>>>(zi, wo, bo, out);
}

// Round 4
// 397.064 us; speedup vs baseline: 1.6716x; 1.6716x over previous
//
#include <hip/hip_runtime.h>
#include <hip/hip_bf16.h>
#include <cstddef>

#define B_ 16
#define T_ 64
#define N_ 1024
#define D_ 32
#define H_ 64
#define C_ 32
#define O_ 12

typedef __attribute__((ext_vector_type(8))) short bf16x8;
typedef __attribute__((ext_vector_type(4))) float f32x4;
#define MFMA16(a,b,c) __builtin_amdgcn_mfma_f32_16x16x32_bf16(a,b,c,0,0,0)

__device__ __forceinline__ float d_tanhf(float v){ float e = __expf(2.f*v); return 1.f - 2.f/(e + 1.f); }
__device__ __forceinline__ float d_sigmf(float v){ return 1.f/(1.f + __expf(-v)); }
__device__ __forceinline__ short f2bs(float f){
  __hip_bfloat16 h = __float2bfloat16(f);
  union { __hip_bfloat16 b; short s; } u; u.b = h; return u.s;
}

// ---------------- K1: Ubf[b,n,0:64]=bf16(m1), [64:128]=bf16(m2) ----------------
__global__ __launch_bounds__(128) void k_u(const float* __restrict__ x,
    const float* __restrict__ w1, const float* __restrict__ b1,
    const float* __restrict__ w2, const float* __restrict__ b2,
    unsigned short* __restrict__ Ubf)
{
  int row = blockIdx.x;               // b*N + n
  int b = row >> 10, n = row & (N_-1);
  int t = threadIdx.x;
  int hh = t & (H_-1), which = t >> 6;
  __shared__ float xl[D_];
  if (t < D_) xl[t] = x[(((size_t)b*T_ + (T_-1))*N_ + n)*D_ + t];
  __syncthreads();
  const float* w  = which ? w2 : w1;
  const float* bi = which ? b2 : b1;
  float acc = bi[hh];
  #pragma unroll
  for (int d = 0; d < D_; ++d) acc += xl[d] * w[d*H_ + hh];
  Ubf[(size_t)row*128 + which*H_ + hh] = (unsigned short)f2bs(acc);
}

// ---------------- K2: adj = softmax(tanh(S)) via MFMA, exp in registers ----------------
// S[n,m] = sum_k U[n,k]*U[m,(k+64)&127]. Block: 512 thr = 8 waves; wave = 16 rows x 512 cols.
__global__ __launch_bounds__(512, 1) void k_adj(const unsigned short* __restrict__ Ubf,
                                                float* __restrict__ adj)
{
  __shared__ float rsum[2][64];
  int b  = blockIdx.x >> 4;
  int n0 = (blockIdx.x & 15) * 64;
  int tid = threadIdx.x;
  int w = tid >> 6, l = tid & 63;
  int wr = w & 3, wc = w >> 2;        // row-group (16 rows), col-half (512 cols)
  int l15 = l & 15, lg = l >> 4;      // lg 0..3
  const unsigned short* Ub = Ubf + (size_t)b*N_*128;

  // A-frags: rows n0+16*wr+l15, k-chunks of 32
  bf16x8 afr[4];
  #pragma unroll
  for (int kc = 0; kc < 4; ++kc)
    afr[kc] = *reinterpret_cast<const bf16x8*>(Ub + (size_t)(n0 + 16*wr + l15)*128 + 32*kc + 8*lg);

  f32x4 acc[32];
  #pragma unroll
  for (int ct = 0; ct < 32; ++ct) acc[ct] = (f32x4){0.f,0.f,0.f,0.f};

  #pragma unroll
  for (int ct = 0; ct < 32; ++ct) {
    const unsigned short* Um = Ub + (size_t)(512*wc + 16*ct + l15)*128;
    #pragma unroll
    for (int kc = 0; kc < 4; ++kc) {
      int ks = (32*kc + 8*lg + 64) & 127;   // swapped-halves B operand
      bf16x8 bfr = *reinterpret_cast<const bf16x8*>(Um + ks);
      acc[ct] = MFMA16(afr[kc], bfr, acc[ct]);
    }
  }

  // epilogue: exp(tanh(S)) in-place, row partial sums
  float rs[4] = {0.f,0.f,0.f,0.f};
  #pragma unroll
  for (int ct = 0; ct < 32; ++ct) {
    #pragma unroll
    for (int r = 0; r < 4; ++r) {
      float e = __expf(d_tanhf(acc[ct][r]));
      acc[ct][r] = e;
      rs[r] += e;
    }
  }
  #pragma unroll
  for (int r = 0; r < 4; ++r) {
    float s = rs[r];
    s += __shfl_xor(s, 1); s += __shfl_xor(s, 2);
    s += __shfl_xor(s, 4); s += __shfl_xor(s, 8);
    rs[r] = s;
  }
  if (l15 == 0) {
    #pragma unroll
    for (int r = 0; r < 4; ++r)
      rsum[wc][16*wr + 4*lg + r] = rs[r];
  }
  __syncthreads();
  float inv[4];
  #pragma unroll
  for (int r = 0; r < 4; ++r) {
    int row = 16*wr + 4*lg + r;
    inv[r] = 1.0f / (rsum[0][row] + rsum[1][row]);
  }
  #pragma unroll
  for (int ct = 0; ct < 32; ++ct) {
    #pragma unroll
    for (int r = 0; r < 4; ++r) {
      int n = n0 + 16*wr + 4*lg + r;
      int m = 512*wc + 16*ct + l15;
      adj[((size_t)b*N_ + n)*N_ + m] = acc[ct][r] * inv[r];
    }
  }
}

// ---------------- K3: gated dilated convs, last-position only -> h ----------------
__global__ __launch_bounds__(256) void k_conv(const float* __restrict__ x,
    const float* __restrict__ fw1,const float* __restrict__ fb1,const float* __restrict__ gw1,const float* __restrict__ gb1,
    const float* __restrict__ fw2,const float* __restrict__ fb2,const float* __restrict__ gw2,const float* __restrict__ gb2,
    const float* __restrict__ fw3,const float* __restrict__ fb3,const float* __restrict__ gw3,const float* __restrict__ gb3,
    float* __restrict__ h)
{
  __shared__ float xs[16][15][32];
  __shared__ float y1[16][7][32];
  __shared__ float y2[16][3][32];
  int tid = threadIdx.x;
  int b  = blockIdx.x >> 6;
  int n0 = (blockIdx.x & 63) * 16;

  for (int l = tid; l < 1920; l += 256) {
    int t = l >> 7, r = l & 127;
    int nl = r >> 3, d4 = r & 7;
    float4 v = reinterpret_cast<const float4*>(x)[(((size_t)b*T_ + 49 + t)*N_ + n0 + nl)*8 + d4];
    *reinterpret_cast<float4*>(&xs[nl][t][d4*4]) = v;
  }
  __syncthreads();

  int sg = tid >> 5, c = tid & 31;

  float af[2][7], ag[2][7];
  {
    float bf = fb1[c], bg = gb1[c];
    #pragma unroll
    for (int ss=0; ss<2; ++ss)
      #pragma unroll
      for (int p=0;p<7;++p){ af[ss][p]=bf; ag[ss][p]=bg; }
  }
  for (int icb = 0; icb < 4; ++icb) {
    float wfl[24], wgl[24];
    #pragma unroll
    for (int q = 0; q < 6; ++q) {
      float4 a = reinterpret_cast<const float4*>(fw1)[c*24 + icb*6 + q];
      float4 g = reinterpret_cast<const float4*>(gw1)[c*24 + icb*6 + q];
      wfl[q*4+0]=a.x; wfl[q*4+1]=a.y; wfl[q*4+2]=a.z; wfl[q*4+3]=a.w;
      wgl[q*4+0]=g.x; wgl[q*4+1]=g.y; wgl[q*4+2]=g.z; wgl[q*4+3]=g.w;
    }
    #pragma unroll
    for (int ic8 = 0; ic8 < 8; ++ic8) {
      int ic = icb*8 + ic8;
      #pragma unroll
      for (int ss=0; ss<2; ++ss) {
        int s = sg*2 + ss;
        float xv[15];
        #pragma unroll
        for (int t=0;t<15;++t) xv[t] = xs[s][t][ic];
        #pragma unroll
        for (int p=0;p<7;++p){
          #pragma unroll
          for (int k=0;k<3;++k){
            af[ss][p] += xv[2*p+k]*wfl[ic8*3+k];
            ag[ss][p] += xv[2*p+k]*wgl[ic8*3+k];
          }
        }
      }
    }
  }
  #pragma unroll
  for (int ss=0; ss<2; ++ss)
    #pragma unroll
    for (int p=0;p<7;++p) y1[sg*2+ss][p][c] = d_tanhf(af[ss][p]) * d_sigmf(ag[ss][p]);
  __syncthreads();

  float af2[2][3], ag2[2][3];
  {
    float bf = fb2[c], bg = gb2[c];
    #pragma unroll
    for (int ss=0; ss<2; ++ss)
      #pragma unroll
      for (int r=0;r<3;++r){ af2[ss][r]=bf; ag2[ss][r]=bg; }
  }
  for (int icb = 0; icb < 4; ++icb) {
    float wfl[24], wgl[24];
    #pragma unroll
    for (int q = 0; q < 6; ++q) {
      float4 a = reinterpret_cast<const float4*>(fw2)[c*24 + icb*6 + q];
      float4 g = reinterpret_cast<const float4*>(gw2)[c*24 + icb*6 + q];
      wfl[q*4+0]=a.x; wfl[q*4+1]=a.y; wfl[q*4+2]=a.z; wfl[q*4+3]=a.w;
      wgl[q*4+0]=g.x; wgl[q*4+1]=g.y; wgl[q*4+2]=g.z; wgl[q*4+3]=g.w;
    }
    #pragma unroll
    for (int ic8 = 0; ic8 < 8; ++ic8) {
      int ic = icb*8 + ic8;
      #pragma unroll
      for (int ss=0; ss<2; ++ss) {
        int s = sg*2 + ss;
        float yv[7];
        #pragma unroll
        for (int j=0;j<7;++j) yv[j] = y1[s][j][ic];
        #pragma unroll
        for (int r=0;r<3;++r){
          #pragma unroll
          for (int k=0;k<3;++k){
            af2[ss][r] += yv[2*r+k]*wfl[ic8*3+k];
            ag2[ss][r] += yv[2*r+k]*wgl[ic8*3+k];
          }
        }
      }
    }
  }
  #pragma unroll
  for (int ss=0; ss<2; ++ss)
    #pragma unroll
    for (int r=0;r<3;++r) y2[sg*2+ss][r][c] = d_tanhf(af2[ss][r]) * d_sigmf(ag2[ss][r]);
  __syncthreads();

  float af3[2], ag3[2];
  {
    float bf = fb3[c], bg = gb3[c];
    af3[0]=bf; af3[1]=bf; ag3[0]=bg; ag3[1]=bg;
  }
  for (int icb = 0; icb < 4; ++icb) {
    float wfl[24], wgl[24];
    #pragma unroll
    for (int q = 0; q < 6; ++q) {
      float4 a = reinterpret_cast<const float4*>(fw3)[c*24 + icb*6 + q];
      float4 g = reinterpret_cast<const float4*>(gw3)[c*24 + icb*6 + q];
      wfl[q*4+0]=a.x; wfl[q*4+1]=a.y; wfl[q*4+2]=a.z; wfl[q*4+3]=a.w;
      wgl[q*4+0]=g.x; wgl[q*4+1]=g.y; wgl[q*4+2]=g.z; wgl[q*4+3]=g.w;
    }
    #pragma unroll
    for (int ic8 = 0; ic8 < 8; ++ic8) {
      int ic = icb*8 + ic8;
      #pragma unroll
      for (int ss=0; ss<2; ++ss) {
        int s = sg*2 + ss;
        float yv[3];
        #pragma unroll
        for (int r=0;r<3;++r) yv[r] = y2[s][r][ic];
        #pragma unroll
        for (int k=0;k<3;++k){
          af3[ss] += yv[k]*wfl[ic8*3+k];
          ag3[ss] += yv[k]*wgl[ic8*3+k];
        }
      }
    }
  }
  #pragma unroll
  for (int ss=0; ss<2; ++ss)
    h[((size_t)b*N_ + n0 + sg*2 + ss)*C_ + c] = d_tanhf(af3[ss]) * d_sigmf(ag3[ss]);
}

// ---------------- K3b: zbT0[b][c][n] = bf16(h[b][n][c]) ----------------
__global__ __launch_bounds__(256) void k_zb(const float* __restrict__ h, unsigned short* __restrict__ zbT)
{
  __shared__ float t[32][33];
  int b = blockIdx.x >> 5, n0 = (blockIdx.x & 31) * 32;
  int tid = threadIdx.x;
  {
    int r = tid >> 3, c4 = tid & 7;
    float4 v = reinterpret_cast<const float4*>(h + ((size_t)b*N_ + n0 + r)*32)[c4];
    t[r][c4*4+0]=v.x; t[r][c4*4+1]=v.y; t[r][c4*4+2]=v.z; t[r][c4*4+3]=v.w;
  }
  __syncthreads();
  int c = tid >> 3, ng = (tid & 7) * 4;
  unsigned int p0 = (unsigned int)(unsigned short)f2bs(t[ng+0][c]) | ((unsigned int)(unsigned short)f2bs(t[ng+1][c]) << 16);
  unsigned int p1 = (unsigned int)(unsigned short)f2bs(t[ng+2][c]) | ((unsigned int)(unsigned short)f2bs(t[ng+3][c]) << 16);
  uint2 val; val.x = p0; val.y = p1;
  *reinterpret_cast<uint2*>(zbT + ((size_t)b*32 + c)*N_ + n0 + ng) = val;
}

// ---------------- K4: z' = 0.1h + 0.45z + 0.45 adj@z via MFMA ----------------
// Block 256 thr = 4 waves; wave = 16 rows x 16 cols, full K=1024. Grid: 16 b x 32 rowgroups.
__global__ __launch_bounds__(256) void k_propm(const float* __restrict__ adj,
    const unsigned short* __restrict__ zbT, const float* __restrict__ h,
    const float* __restrict__ zin, float* __restrict__ zout,
    unsigned short* __restrict__ zbTout)
{
  int b = blockIdx.x >> 5;
  int g = blockIdx.x & 31;
  int tid = threadIdx.x;
  int w = tid >> 6, l = tid & 63;
  int wr = w >> 1, wc = w & 1;
  int l15 = l & 15, lg = l >> 4;
  int n_base = g*32 + 16*wr;

  const float* A = adj + ((size_t)b*N_ + n_base + l15)*N_;
  const unsigned short* Z = zbT + ((size_t)b*32 + 16*wc + l15)*N_;

  f32x4 acc = {0.f,0.f,0.f,0.f};
  #pragma unroll 8
  for (int kc = 0; kc < 32; ++kc) {
    int k0 = 32*kc + 8*lg;
    f32x4 a0 = *reinterpret_cast<const f32x4*>(A + k0);
    f32x4 a1 = *reinterpret_cast<const f32x4*>(A + k0 + 4);
    bf16x8 bfr = *reinterpret_cast<const bf16x8*>(Z + k0);
    bf16x8 afr;
    afr[0]=f2bs(a0[0]); afr[1]=f2bs(a0[1]); afr[2]=f2bs(a0[2]); afr[3]=f2bs(a0[3]);
    afr[4]=f2bs(a1[0]); afr[5]=f2bs(a1[1]); afr[6]=f2bs(a1[2]); afr[7]=f2bs(a1[3]);
    acc = MFMA16(afr, bfr, acc);
  }

  int c = 16*wc + l15;
  #pragma unroll
  for (int r = 0; r < 4; ++r) {
    int n = n_base + 4*lg + r;
    size_t idx = ((size_t)b*N_ + n)*32 + c;
    float v = 0.1f*h[idx] + 0.45f*zin[idx] + 0.45f*acc[r];
    zout[idx] = v;
    zbTout[((size_t)b*32 + c)*N_ + n] = (unsigned short)f2bs(v);
  }
}

// ---------------- K5: out = relu(z) @ wo + bo ----------------
__global__ __launch_bounds__(256) void k_out(const float* __restrict__ z, const float* __restrict__ wo,
                                             const float* __restrict__ bo, float* __restrict__ out)
{
  int gid = blockIdx.x*256 + threadIdx.x;
  if (gid >= B_*N_*O_) return;
  int o = gid % O_; int row = gid / O_;
  const float* zr = z + (size_t)row*C_;
  float acc = bo[o];
  #pragma unroll
  for (int cc = 0; cc < C_; ++cc) acc += fmaxf(zr[cc], 0.f) * wo[cc*O_ + o];
  out[gid] = acc;
}

extern "C" void kernel_launch(void* const* d_in, const int* in_sizes, int n_in,
                              void* d_out, int out_size, void* d_ws, size_t ws_size,
                              hipStream_t stream)
{
  const float* x   = (const float*)d_in[0];
  const float* w1  = (const float*)d_in[1];
  const float* b1  = (const float*)d_in[2];
  const float* w2  = (const float*)d_in[3];
  const float* b2  = (const float*)d_in[4];
  const float* fw1 = (const float*)d_in[5];  const float* fb1 = (const float*)d_in[6];
  const float* gw1 = (const float*)d_in[7];  const float* gb1 = (const float*)d_in[8];
  const float* fw2 = (const float*)d_in[9];  const float* fb2 = (const float*)d_in[10];
  const float* gw2 = (const float*)d_in[11]; const float* gb2 = (const float*)d_in[12];
  const float* fw3 = (const float*)d_in[13]; const float* fb3 = (const float*)d_in[14];
  const float* gw3 = (const float*)d_in[15]; const float* gb3 = (const float*)d_in[16];
  const float* wo  = (const float*)d_in[17]; const float* bo  = (const float*)d_in[18];

  float* out = (float*)d_out;
  float* adj = out + (size_t)B_*N_*O_;

  char* ws = (char*)d_ws;
  unsigned short* Ubf  = (unsigned short*)ws;                       // 4 MB
  float* h             = (float*)(ws + (4u<<20));                   // 2 MB
  float* z0            = (float*)(ws + (6u<<20));                   // 2 MB
  float* z1            = (float*)(ws + (8u<<20));                   // 2 MB
  unsigned short* zbT0 = (unsigned short*)(ws + (10u<<20));         // 1 MB
  unsigned short* zbT1 = (unsigned short*)(ws + (11u<<20));         // 1 MB

  k_u<<<B_*N_, 128, 0, stream>>>(x, w1, b1, w2, b2, Ubf);
  k_adj<<<B_*16, 512, 0, stream>>>(Ubf, adj);
  k_conv<<<B_*N_/16, 256, 0, stream>>>(x, fw1,fb1,gw1,gb1, fw2,fb2,gw2,gb2, fw3,fb3,gw3,gb3, h);
  k_zb<<<B_*32, 256, 0, stream>>>(h, zbT0);

  const float* zi = h;
  const unsigned short* zbi = zbT0;
  float* zfbuf[2] = {z0, z1};
  unsigned short* zbbuf[2] = {zbT1, zbT0};
  for (int it = 0; it < 10; ++it) {
    float* zo = zfbuf[it & 1];
    unsigned short* zbo = zbbuf[it & 1];
    k_propm<<<B_*32, 256, 0, stream>>>(adj, zbi, h, zi, zo, zbo);
    zi = zo; zbi = zbo;
  }
  k_out<<<(B_*N_*O_ + 255)/256, 256, 0, stream>>>(zi, wo, bo, out);
}